// Round 2
// baseline (136.100 us; speedup 1.0000x reference)
//
#include <hip/hip_runtime.h>
#include <math.h>

// Problem constants (from reference): T=128, B=2048, D=256, ALPHA=0.5, VTH=1.0
#define TT 128
#define BB 2048
#define DDIM 256
#define BD (BB * DDIM)

// GL coefficients c[j] = prod_{i=1..j} (1 - (1+alpha)/i), computed in f64 then
// cast to f32 — exactly mirrors _gl_coeffs (float64 cumprod -> float32 cast).
struct Coeffs {
    float c[TT + 1];
};
static constexpr Coeffs make_coeffs() {
    Coeffs r{};
    r.c[0] = 1.0f;
    double cur = 1.0;
    for (int j = 1; j <= TT; ++j) {
        cur *= (1.0 - 1.5 / (double)j);  // (1+alpha) = 1.5
        r.c[j] = (float)cur;
    }
    return r;
}
static constexpr Coeffs CO = make_coeffs();

// One thread per (b,d) sequence. Full y-history in arch VGPRs:
// __launch_bounds__(256, 2) -> 256-VGPR budget (2 waves/SIMD), so y[128]
// stays directly addressable (no accvgpr spill traffic). Both loops fully
// unrolled so all y[] indices are compile-time constants.
__global__ __launch_bounds__(256, 2) void gl_if_kernel(const float* __restrict__ x,
                                                       float* __restrict__ sp) {
    const int g = blockIdx.x * 256 + threadIdx.x;  // (b,d) flat index
    const float* __restrict__ xp = x + g;
    float* __restrict__ spp = sp + g;
    float y[TT];  // y[i] = reset membrane of step i+1

#pragma unroll
    for (int k = 1; k <= TT; ++k) {
        const float xk = *xp;
        xp += BD;  // pointer bump: SALU base advance instead of per-lane addr math
        // right = sum over buffer slots i < k-1 of c[k-1-i] * y[i]
        float acc = 0.0f;
#pragma unroll
        for (int i = 0; i <= k - 2; ++i) {
            acc = fmaf(CO.c[k - 1 - i], y[i], acc);
        }
        const float men0 = xk - acc;
        const float spike = (men0 > 1.0f) ? 1.0f : 0.0f;
        y[k - 1] = men0 - spike;  // VTH = 1.0
        *spp = spike;
        spp += BD;
    }
}

// Lorentz expmap: per row b, vv = -v0^2 + sum_{d>=1} vd^2; s = sqrt(max(vv,eps));
// out = cosh(s)*z + (sinh(s)/s)*v.  One block per row, one thread per d.
__global__ __launch_bounds__(256) void expmap_kernel(const float* __restrict__ v,
                                                     const float* __restrict__ z,
                                                     float* __restrict__ out) {
    const int b = blockIdx.x;
    const int d = threadIdx.x;
    const size_t idx = (size_t)b * DDIM + d;
    const float vd = v[idx];

    float term = vd * vd;
    if (d == 0) term = -term;

    // reduce across the 256-thread block (4 waves of 64)
    float sum = term;
#pragma unroll
    for (int off = 32; off > 0; off >>= 1) sum += __shfl_down(sum, off, 64);

    __shared__ float ws[4];
    if ((threadIdx.x & 63) == 0) ws[threadIdx.x >> 6] = sum;
    __syncthreads();
    const float vv = ws[0] + ws[1] + ws[2] + ws[3];

    const float s2 = fmaxf(vv, 1e-6f);
    const float s = sqrtf(s2);
    const float ch = coshf(s);
    const float shs = sinhf(s) / s;

    out[idx] = ch * z[idx] + shs * vd;
}

extern "C" void kernel_launch(void* const* d_in, const int* in_sizes, int n_in,
                              void* d_out, int out_size, void* d_ws, size_t ws_size,
                              hipStream_t stream) {
    const float* x_seq = (const float*)d_in[0];
    const float* v_seq = (const float*)d_in[1];
    const float* z_seq = (const float*)d_in[2];

    float* s_out = (float*)d_out;                       // [T,B,D] spikes
    float* z_out = (float*)d_out + (size_t)TT * BD;     // [B,D] expmap

    gl_if_kernel<<<BD / 256, 256, 0, stream>>>(x_seq, s_out);
    expmap_kernel<<<BB, DDIM, 0, stream>>>(v_seq, z_seq, z_out);
}

// Round 3
// 134.265 us; speedup vs baseline: 1.0137x; 1.0137x over previous
//
#include <hip/hip_runtime.h>
#include <math.h>

// Problem constants (from reference): T=128, B=2048, D=256, ALPHA=0.5, VTH=1.0
#define TT 128
#define BB 2048
#define DDIM 256
#define BD (BB * DDIM)

// GL coefficients c[j] = prod_{i=1..j} (1 - (1+alpha)/i), computed in f64 then
// cast to f32 — exactly mirrors _gl_coeffs (float64 cumprod -> float32 cast).
struct Coeffs {
    float c[TT + 1];
};
static constexpr Coeffs make_coeffs() {
    Coeffs r{};
    r.c[0] = 1.0f;
    double cur = 1.0;
    for (int j = 1; j <= TT; ++j) {
        cur *= (1.0 - 1.5 / (double)j);  // (1+alpha) = 1.5
        r.c[j] = (float)cur;
    }
    return r;
}
static constexpr Coeffs CO = make_coeffs();

// One thread per (b,d) sequence, full y-history in registers.
// amdgpu_waves_per_eu(1): min-occupancy 1 wave/EU -> 512-reg budget so the
// allocator has no reason to shuttle y[] through AGPRs (the R1/R2 kernels
// sat at 72 arch VGPRs + ~128 AGPRs, paying ~1 v_accvgpr_read per FMA).
// amdgpu_flat_work_group_size(256,256): exact block size, tightest constraint.
__global__ __attribute__((amdgpu_flat_work_group_size(256, 256),
                          amdgpu_waves_per_eu(1)))
void gl_if_kernel(const float* __restrict__ x, float* __restrict__ sp) {
    const int g = blockIdx.x * 256 + threadIdx.x;  // (b,d) flat index
    const float* __restrict__ xp = x + g;
    float* __restrict__ spp = sp + g;
    float y[TT];  // y[i] = reset membrane of step i+1

    float xk = *xp;  // prefetch depth 1: cover load latency at low occupancy
    xp += BD;

#pragma unroll
    for (int k = 1; k <= TT; ++k) {
        float xnext = 0.0f;
        if (k < TT) {
            xnext = *xp;
            xp += BD;
        }
        // right = sum over buffer slots i < k-1 of c[k-1-i] * y[i]
        // (slot-ascending order = reference tensordot order; single chain,
        //  bit-identical to the R1 kernel that passed)
        float acc = 0.0f;
#pragma unroll
        for (int i = 0; i <= k - 2; ++i) {
            acc = fmaf(CO.c[k - 1 - i], y[i], acc);
        }
        const float men0 = xk - acc;
        const float spike = (men0 > 1.0f) ? 1.0f : 0.0f;
        y[k - 1] = men0 - spike;  // VTH = 1.0
        *spp = spike;
        spp += BD;
        xk = xnext;
    }
}

// Lorentz expmap: per row b, vv = -v0^2 + sum_{d>=1} vd^2; s = sqrt(max(vv,eps));
// out = cosh(s)*z + (sinh(s)/s)*v.  One block per row, one thread per d.
__global__ __launch_bounds__(256) void expmap_kernel(const float* __restrict__ v,
                                                     const float* __restrict__ z,
                                                     float* __restrict__ out) {
    const int b = blockIdx.x;
    const int d = threadIdx.x;
    const size_t idx = (size_t)b * DDIM + d;
    const float vd = v[idx];

    float term = vd * vd;
    if (d == 0) term = -term;

    // reduce across the 256-thread block (4 waves of 64)
    float sum = term;
#pragma unroll
    for (int off = 32; off > 0; off >>= 1) sum += __shfl_down(sum, off, 64);

    __shared__ float ws[4];
    if ((threadIdx.x & 63) == 0) ws[threadIdx.x >> 6] = sum;
    __syncthreads();
    const float vv = ws[0] + ws[1] + ws[2] + ws[3];

    const float s2 = fmaxf(vv, 1e-6f);
    const float s = sqrtf(s2);
    const float ch = coshf(s);
    const float shs = sinhf(s) / s;

    out[idx] = ch * z[idx] + shs * vd;
}

extern "C" void kernel_launch(void* const* d_in, const int* in_sizes, int n_in,
                              void* d_out, int out_size, void* d_ws, size_t ws_size,
                              hipStream_t stream) {
    const float* x_seq = (const float*)d_in[0];
    const float* v_seq = (const float*)d_in[1];
    const float* z_seq = (const float*)d_in[2];

    float* s_out = (float*)d_out;                       // [T,B,D] spikes
    float* z_out = (float*)d_out + (size_t)TT * BD;     // [B,D] expmap

    gl_if_kernel<<<BD / 256, 256, 0, stream>>>(x_seq, s_out);
    expmap_kernel<<<BB, DDIM, 0, stream>>>(v_seq, z_seq, z_out);
}